// Round 5
// baseline (2808.908 us; speedup 1.0000x reference)
//
#include <hip/hip_runtime.h>
#include <hip/hip_bf16.h>
#include <hip/hip_fp16.h>

// GRU B=64 S=2048 I=256 H=256, fp32 in/out.
// Phase 1: XG[m][768] = x@[Wz|Wr|Wh] + bias  (fp16 MFMA, fp32 accum)
// Phase 2: 64 WGs x 512 threads, waves_per_eu(2,2) (256-reg budget; the
//   default allocator self-targets 6 waves/EU and remats U loads into the
//   loop -- R1/R2 lesson). Thread (j=tid&255, s=tid>>8) owns all 3 gates
//   of column j, K-half s. s is WAVE-UNIFORM: R4 lesson -- lane-pair split
//   made every h ds_read_b128 a 2-address/4-extra-cycle bank access
//   (SQ_LDS_BANK_CONFLICT = 4x read count). Uniform s => all 64 lanes read
//   the SAME LDS address => pure broadcast, 0 conflicts. K-half partials
//   combined via part[3][256] LDS (no ds_swizzle shuffles), 2 barriers/step.

#define S_LEN 2048
#define BATCH 64
#define HDIM  256
#define NGATE 768
#define M_TOTAL (BATCH * S_LEN)  // 131072

typedef _Float16 h2_t __attribute__((ext_vector_type(2)));
typedef _Float16 h8_t __attribute__((ext_vector_type(8)));
typedef float    f32x4 __attribute__((ext_vector_type(4)));

static __device__ __forceinline__ h2_t as_h2(unsigned u) {
    h2_t r; __builtin_memcpy(&r, &u, 4); return r;
}
static __device__ __forceinline__ float h2f(unsigned short s) {
    _Float16 h; __builtin_memcpy(&h, &s, 2); return (float)h;
}
static __device__ __forceinline__ unsigned short f2h(float f) {
    _Float16 h = (_Float16)f; unsigned short s; __builtin_memcpy(&s, &h, 2); return s;
}

static __device__ __forceinline__ float dot2(unsigned h, unsigned u, float acc) {
#if __has_builtin(__builtin_amdgcn_fdot2)
    return __builtin_amdgcn_fdot2(as_h2(h), as_h2(u), acc, false);
#else
    h2_t a = as_h2(h), b = as_h2(u);
    return acc + (float)a[0] * (float)b[0] + (float)a[1] * (float)b[1];
#endif
}

static __device__ __forceinline__ float sigmoid_fast(float x) {
    float e = __builtin_amdgcn_exp2f(-1.44269504088896341f * x);
    return __builtin_amdgcn_rcpf(1.0f + e);
}
static __device__ __forceinline__ float tanh_fast(float x) {
    return 2.0f * sigmoid_fast(2.0f * x) - 1.0f;
}

// ---------------- prep kernels ----------------

__global__ void k_cvt_x(const float4* __restrict__ x4, ushort4* __restrict__ xh4) {
    int i = blockIdx.x * blockDim.x + threadIdx.x;
    float4 v = x4[i];
    ushort4 o;
    o.x = f2h(v.x); o.y = f2h(v.y); o.z = f2h(v.z); o.w = f2h(v.w);
    xh4[i] = o;
}

__global__ void k_prep_w(const float* __restrict__ Wz, const float* __restrict__ Wr,
                         const float* __restrict__ Wh,
                         const float* __restrict__ bz, const float* __restrict__ br,
                         const float* __restrict__ bh,
                         const float* __restrict__ buz, const float* __restrict__ bur,
                         unsigned short* __restrict__ Wt, float* __restrict__ biascat) {
    int n = blockIdx.x;       // 0..767
    int k = threadIdx.x;      // 0..255
    int g = n >> 8, h = n & 255;
    const float* W = (g == 0) ? Wz : (g == 1) ? Wr : Wh;
    Wt[n * 256 + k] = f2h(W[k * 256 + h]);
    if (k == 0) {
        float bias = (g == 0) ? (bz[h] + buz[h]) : (g == 1) ? (br[h] + bur[h]) : bh[h];
        biascat[n] = bias;
    }
}

// Upk[(g*128+k2)*256 + j] = pack(fp16(Ug[2k2][j]), fp16(Ug[2k2+1][j]))
__global__ void k_prep_u(const float* __restrict__ Uz, const float* __restrict__ Ur,
                         const float* __restrict__ Uh, unsigned* __restrict__ Upk) {
    int idx = blockIdx.x * 256 + threadIdx.x;  // 0..98303
    int j  = idx & 255;
    int k2 = (idx >> 8) & 127;
    int g  = idx >> 15;
    const float* U = (g == 0) ? Uz : (g == 1) ? Ur : Uh;
    unsigned lo = f2h(U[(2 * k2) * 256 + j]);
    unsigned hi = f2h(U[(2 * k2 + 1) * 256 + j]);
    Upk[idx] = lo | (hi << 16);
}

// ---------------- phase 1: input GEMM ----------------

#define LDT 264  // 256 + 8 halves per LDS row

__global__ __launch_bounds__(256) void k_gemm_x(const unsigned short* __restrict__ Xh,
                                                const unsigned short* __restrict__ Wt,
                                                const float* __restrict__ biascat,
                                                unsigned short* __restrict__ XG) {
    __shared__ unsigned short As[128 * LDT];
    __shared__ unsigned short Bs[128 * LDT];
    int tid = threadIdx.x;
    int m0 = blockIdx.x * 128;
    int n0 = blockIdx.y * 128;

    {
        const unsigned short* ga = Xh + (size_t)m0 * 256;
        const unsigned short* gb = Wt + (size_t)n0 * 256;
#pragma unroll
        for (int i = 0; i < 16; i++) {
            int chunk = tid + i * 256;
            int row = chunk >> 5;
            int c8  = (chunk & 31) * 8;
            uint4 va = *(const uint4*)(ga + row * 256 + c8);
            *(uint4*)(As + row * LDT + c8) = va;
            uint4 vb = *(const uint4*)(gb + row * 256 + c8);
            *(uint4*)(Bs + row * LDT + c8) = vb;
        }
    }
    __syncthreads();

    int lane = tid & 63, wv = tid >> 6;
    int mw = (wv & 1) * 64, nw = (wv >> 1) * 64;
    int lr = lane & 15, lg = lane >> 4;

    f32x4 acc[4][4] = {};
#pragma unroll
    for (int k = 0; k < 8; k++) {
        h8_t a[4], b[4];
#pragma unroll
        for (int i = 0; i < 4; i++)
            a[i] = *(const h8_t*)(As + (mw + i * 16 + lr) * LDT + k * 32 + lg * 8);
#pragma unroll
        for (int jj = 0; jj < 4; jj++)
            b[jj] = *(const h8_t*)(Bs + (nw + jj * 16 + lr) * LDT + k * 32 + lg * 8);
#pragma unroll
        for (int i = 0; i < 4; i++)
#pragma unroll
            for (int jj = 0; jj < 4; jj++)
                acc[i][jj] = __builtin_amdgcn_mfma_f32_16x16x32_f16(a[i], b[jj], acc[i][jj], 0, 0, 0);
    }

#pragma unroll
    for (int jj = 0; jj < 4; jj++) {
        int gcol = n0 + nw + jj * 16 + lr;
        float bias = biascat[gcol];
#pragma unroll
        for (int i = 0; i < 4; i++) {
            int grow = m0 + mw + i * 16 + lg * 4;
#pragma unroll
            for (int r = 0; r < 4; r++) {
                XG[(size_t)(grow + r) * NGATE + gcol] = f2h(acc[i][jj][r] + bias);
            }
        }
    }
}

// ---------------- phase 2: recurrence ----------------

__global__ __launch_bounds__(512) __attribute__((amdgpu_waves_per_eu(2, 2)))
void k_gru(const unsigned* __restrict__ Upk,
           const unsigned short* __restrict__ XG,
           const float* __restrict__ buh,
           float* __restrict__ out) {
    __shared__ __align__(16) unsigned short hb[2][256];
    __shared__ float part[3][256];
    int tid = threadIdx.x;
    int j = tid & 255, s = tid >> 8;   // s is wave-uniform (waves 0-3: s=0)
    int b = blockIdx.x;

    // preamble: 192 packed-fp16 U registers per thread (K-half s)
    unsigned uz[64], ur[64], uh[64];
    {
        const unsigned* base = Upk + (size_t)(s * 64) * 256 + j;
#pragma unroll
        for (int k = 0; k < 64; k++) uz[k] = base[k * 256];
#pragma unroll
        for (int k = 0; k < 64; k++) ur[k] = base[(128 + k) * 256];
#pragma unroll
        for (int k = 0; k < 64; k++) uh[k] = base[(256 + k) * 256];
    }
    // pin: asm-touched values cannot be rematerialized
#pragma unroll
    for (int k = 0; k < 64; k++) {
        asm volatile("" : "+v"(uz[k]), "+v"(ur[k]), "+v"(uh[k]));
    }

    float buh_j = 0.0f;
    if (s == 0) buh_j = buh[j];
    if (tid < 256) { hb[0][tid] = 0; hb[1][tid] = 0; }

    const unsigned short* xgp = XG + (size_t)b * S_LEN * NGATE + j;
    float* ob = out + (size_t)b * S_LEN * HDIM + j;

    // t=0 gate-input prefetch: only s=0 (tail owner) needs x
    unsigned short pz = 0, pr = 0, ph = 0;
    if (s == 0) { pz = xgp[0]; pr = xgp[256]; ph = xgp[512]; }
    float hm = 0.0f;  // fp32 master h (s=0 waves)
    __syncthreads();

    for (int t = 0; t < S_LEN; ++t) {
        int cur = t & 1;

        float az0 = 0.f, az1 = 0.f, ar0 = 0.f, ar1 = 0.f, ah0 = 0.f, ah1 = 0.f;
        const uint4* hrow = (const uint4*)hb[cur] + s * 16;  // uniform addr per wave
#pragma unroll
        for (int c = 0; c < 16; c++) {
            uint4 hv = hrow[c];
            int k = c * 4;
            az0 = dot2(hv.x, uz[k + 0], az0); az1 = dot2(hv.y, uz[k + 1], az1);
            ar0 = dot2(hv.x, ur[k + 0], ar0); ar1 = dot2(hv.y, ur[k + 1], ar1);
            ah0 = dot2(hv.x, uh[k + 0], ah0); ah1 = dot2(hv.y, uh[k + 1], ah1);
            az0 = dot2(hv.z, uz[k + 2], az0); az1 = dot2(hv.w, uz[k + 3], az1);
            ar0 = dot2(hv.z, ur[k + 2], ar0); ar1 = dot2(hv.w, ur[k + 3], ar1);
            ah0 = dot2(hv.z, uh[k + 2], ah0); ah1 = dot2(hv.w, uh[k + 3], ah1);
        }
        float sz = az0 + az1, sr = ar0 + ar1, sh = ah0 + ah1;
        if (s == 1) { part[0][j] = sz; part[1][j] = sr; part[2][j] = sh; }
        __syncthreads();

        if (s == 0) {
            float xz = h2f(pz), xr = h2f(pr), xh = h2f(ph);
            const unsigned short* nx = xgp + (size_t)((t + 1 < S_LEN) ? t + 1 : t) * NGATE;
            pz = nx[0]; pr = nx[256]; ph = nx[512];

            float z = sigmoid_fast(xz + sz + part[0][j]);
            float r = sigmoid_fast(xr + sr + part[1][j]);
            float cand = tanh_fast(xh + r * (sh + part[2][j] + buh_j));
            hm = (1.0f - z) * hm + z * cand;
            ob[(size_t)t * HDIM] = hm;
            hb[cur ^ 1][j] = f2h(hm);
        }
        __syncthreads();
    }
}

// ---------------- launch ----------------

extern "C" void kernel_launch(void* const* d_in, const int* in_sizes, int n_in,
                              void* d_out, int out_size, void* d_ws, size_t ws_size,
                              hipStream_t stream) {
    const float* x   = (const float*)d_in[0];
    const float* Wz  = (const float*)d_in[1];
    const float* bz  = (const float*)d_in[2];
    const float* Wr  = (const float*)d_in[3];
    const float* br  = (const float*)d_in[4];
    const float* Wh  = (const float*)d_in[5];
    const float* bh  = (const float*)d_in[6];
    const float* Uz  = (const float*)d_in[7];
    const float* buz = (const float*)d_in[8];
    const float* Ur  = (const float*)d_in[9];
    const float* bur = (const float*)d_in[10];
    const float* Uh  = (const float*)d_in[11];
    const float* buh = (const float*)d_in[12];

    char* ws = (char*)d_ws;
    // layout: Xh 64MiB | XG 192MiB | Wt 384KiB | Upk 384KiB | biascat 3KiB
    unsigned short* Xh = (unsigned short*)(ws);
    unsigned short* XG = (unsigned short*)(ws + 67108864);
    unsigned short* Wt = (unsigned short*)(ws + 268435456);
    unsigned*       Upk = (unsigned*)(ws + 268828672);
    float*          biascat = (float*)(ws + 269221888);

    k_cvt_x<<<32768, 256, 0, stream>>>((const float4*)x, (ushort4*)Xh);
    k_prep_w<<<768, 256, 0, stream>>>(Wz, Wr, Wh, bz, br, bh, buz, bur, Wt, biascat);
    k_prep_u<<<384, 256, 0, stream>>>(Uz, Ur, Uh, Upk);

    dim3 g1(M_TOTAL / 128, NGATE / 128);
    k_gemm_x<<<g1, 256, 0, stream>>>(Xh, Wt, biascat, XG);

    k_gru<<<BATCH, 512, 0, stream>>>(Upk, XG, buh, (float*)d_out);
}

// Round 6
// 2348.867 us; speedup vs baseline: 1.1959x; 1.1959x over previous
//
#include <hip/hip_runtime.h>
#include <hip/hip_bf16.h>
#include <hip/hip_fp16.h>

// GRU B=64 S=2048 I=256 H=256, fp32 in/out.
// Phase 1: XG[m][768] = x@[Wz|Wr|Wh] + bias  (fp16 MFMA, fp32 accum)
// Phase 2: 64 WGs x 512 threads, waves_per_eu(2,2).
//   R4 (best, 2232us): lane-pair split s=tid&1, shfl_xor(1) combine,
//     1 barrier/step -- but h ds_read_b128 hit a 2-address/same-bank
//     pattern: 4 extra cycles per read (SQ_LDS_BANK_CONFLICT = 4x reads).
//   R5: wave-uniform s killed conflicts but cost 2 barriers + serial tail
//     (2667us). Net lesson: keep R4 structure, fix conflict by LAYOUT:
//   h stored interleaved in 16B chunks: chunk c = [h8c..8c+8)|K-half0,
//     then [h128+8c..+8)|K-half1. Lane pair reads A / A+16 -> different
//     banks -> conflict-free broadcast. Everything else = R4.
//   VGPR=116 stable: ~140 U values live in AGPRs (accvgpr_read tax ~2cy/use,
//     no memory traffic) -- accepted this round.

#define S_LEN 2048
#define BATCH 64
#define HDIM  256
#define NGATE 768
#define M_TOTAL (BATCH * S_LEN)  // 131072

typedef _Float16 h2_t __attribute__((ext_vector_type(2)));
typedef _Float16 h8_t __attribute__((ext_vector_type(8)));
typedef float    f32x4 __attribute__((ext_vector_type(4)));

static __device__ __forceinline__ h2_t as_h2(unsigned u) {
    h2_t r; __builtin_memcpy(&r, &u, 4); return r;
}
static __device__ __forceinline__ float h2f(unsigned short s) {
    _Float16 h; __builtin_memcpy(&h, &s, 2); return (float)h;
}
static __device__ __forceinline__ unsigned short f2h(float f) {
    _Float16 h = (_Float16)f; unsigned short s; __builtin_memcpy(&s, &h, 2); return s;
}

static __device__ __forceinline__ float dot2(unsigned h, unsigned u, float acc) {
#if __has_builtin(__builtin_amdgcn_fdot2)
    return __builtin_amdgcn_fdot2(as_h2(h), as_h2(u), acc, false);
#else
    h2_t a = as_h2(h), b = as_h2(u);
    return acc + (float)a[0] * (float)b[0] + (float)a[1] * (float)b[1];
#endif
}

static __device__ __forceinline__ float sigmoid_fast(float x) {
    float e = __builtin_amdgcn_exp2f(-1.44269504088896341f * x);
    return __builtin_amdgcn_rcpf(1.0f + e);
}
static __device__ __forceinline__ float tanh_fast(float x) {
    return 2.0f * sigmoid_fast(2.0f * x) - 1.0f;
}

// ---------------- prep kernels ----------------

__global__ void k_cvt_x(const float4* __restrict__ x4, ushort4* __restrict__ xh4) {
    int i = blockIdx.x * blockDim.x + threadIdx.x;
    float4 v = x4[i];
    ushort4 o;
    o.x = f2h(v.x); o.y = f2h(v.y); o.z = f2h(v.z); o.w = f2h(v.w);
    xh4[i] = o;
}

__global__ void k_prep_w(const float* __restrict__ Wz, const float* __restrict__ Wr,
                         const float* __restrict__ Wh,
                         const float* __restrict__ bz, const float* __restrict__ br,
                         const float* __restrict__ bh,
                         const float* __restrict__ buz, const float* __restrict__ bur,
                         unsigned short* __restrict__ Wt, float* __restrict__ biascat) {
    int n = blockIdx.x;       // 0..767
    int k = threadIdx.x;      // 0..255
    int g = n >> 8, h = n & 255;
    const float* W = (g == 0) ? Wz : (g == 1) ? Wr : Wh;
    Wt[n * 256 + k] = f2h(W[k * 256 + h]);
    if (k == 0) {
        float bias = (g == 0) ? (bz[h] + buz[h]) : (g == 1) ? (br[h] + bur[h]) : bh[h];
        biascat[n] = bias;
    }
}

// Upk[(g*128+k2)*256 + j] = pack(fp16(Ug[2k2][j]), fp16(Ug[2k2+1][j]))
__global__ void k_prep_u(const float* __restrict__ Uz, const float* __restrict__ Ur,
                         const float* __restrict__ Uh, unsigned* __restrict__ Upk) {
    int idx = blockIdx.x * 256 + threadIdx.x;  // 0..98303
    int j  = idx & 255;
    int k2 = (idx >> 8) & 127;
    int g  = idx >> 15;
    const float* U = (g == 0) ? Uz : (g == 1) ? Ur : Uh;
    unsigned lo = f2h(U[(2 * k2) * 256 + j]);
    unsigned hi = f2h(U[(2 * k2 + 1) * 256 + j]);
    Upk[idx] = lo | (hi << 16);
}

// ---------------- phase 1: input GEMM ----------------

#define LDT 264  // 256 + 8 halves per LDS row

__global__ __launch_bounds__(256) void k_gemm_x(const unsigned short* __restrict__ Xh,
                                                const unsigned short* __restrict__ Wt,
                                                const float* __restrict__ biascat,
                                                unsigned short* __restrict__ XG) {
    __shared__ unsigned short As[128 * LDT];
    __shared__ unsigned short Bs[128 * LDT];
    int tid = threadIdx.x;
    int m0 = blockIdx.x * 128;
    int n0 = blockIdx.y * 128;

    {
        const unsigned short* ga = Xh + (size_t)m0 * 256;
        const unsigned short* gb = Wt + (size_t)n0 * 256;
#pragma unroll
        for (int i = 0; i < 16; i++) {
            int chunk = tid + i * 256;
            int row = chunk >> 5;
            int c8  = (chunk & 31) * 8;
            uint4 va = *(const uint4*)(ga + row * 256 + c8);
            *(uint4*)(As + row * LDT + c8) = va;
            uint4 vb = *(const uint4*)(gb + row * 256 + c8);
            *(uint4*)(Bs + row * LDT + c8) = vb;
        }
    }
    __syncthreads();

    int lane = tid & 63, wv = tid >> 6;
    int mw = (wv & 1) * 64, nw = (wv >> 1) * 64;
    int lr = lane & 15, lg = lane >> 4;

    f32x4 acc[4][4] = {};
#pragma unroll
    for (int k = 0; k < 8; k++) {
        h8_t a[4], b[4];
#pragma unroll
        for (int i = 0; i < 4; i++)
            a[i] = *(const h8_t*)(As + (mw + i * 16 + lr) * LDT + k * 32 + lg * 8);
#pragma unroll
        for (int jj = 0; jj < 4; jj++)
            b[jj] = *(const h8_t*)(Bs + (nw + jj * 16 + lr) * LDT + k * 32 + lg * 8);
#pragma unroll
        for (int i = 0; i < 4; i++)
#pragma unroll
            for (int jj = 0; jj < 4; jj++)
                acc[i][jj] = __builtin_amdgcn_mfma_f32_16x16x32_f16(a[i], b[jj], acc[i][jj], 0, 0, 0);
    }

#pragma unroll
    for (int jj = 0; jj < 4; jj++) {
        int gcol = n0 + nw + jj * 16 + lr;
        float bias = biascat[gcol];
#pragma unroll
        for (int i = 0; i < 4; i++) {
            int grow = m0 + mw + i * 16 + lg * 4;
#pragma unroll
            for (int r = 0; r < 4; r++) {
                XG[(size_t)(grow + r) * NGATE + gcol] = f2h(acc[i][jj][r] + bias);
            }
        }
    }
}

// ---------------- phase 2: recurrence ----------------
// h LDS layout (per buffer, 512B): chunk c (c=0..15) occupies bytes
// [c*32, c*32+32): first 16B = h[8c..8c+8) (K-half 0), second 16B =
// h[128+8c..128+8c+8) (K-half 1). Lane pair (s=0,1) reads c*32 + s*16:
// two addresses on DIFFERENT banks -> conflict-free broadcast.

__global__ __launch_bounds__(512) __attribute__((amdgpu_waves_per_eu(2, 2)))
void k_gru(const unsigned* __restrict__ Upk,
           const unsigned short* __restrict__ XG,
           const float* __restrict__ buh,
           float* __restrict__ out) {
    __shared__ __align__(16) unsigned short hb[2][256];
    int tid = threadIdx.x;
    int j = tid >> 1, s = tid & 1;
    int b = blockIdx.x;

    // preamble: 192 packed-fp16 U registers per thread (K-half s)
    unsigned uz[64], ur[64], uh[64];
    {
        const unsigned* base = Upk + (size_t)(s * 64) * 256 + j;
#pragma unroll
        for (int k = 0; k < 64; k++) uz[k] = base[k * 256];
#pragma unroll
        for (int k = 0; k < 64; k++) ur[k] = base[(128 + k) * 256];
#pragma unroll
        for (int k = 0; k < 64; k++) uh[k] = base[(256 + k) * 256];
    }
    // pin: asm-touched values cannot be rematerialized into the loop
#pragma unroll
    for (int k = 0; k < 64; k++) {
        asm volatile("" : "+v"(uz[k]), "+v"(ur[k]), "+v"(uh[k]));
    }

    float buh_j = buh[j];
    if (tid < 256) { hb[0][tid] = 0; hb[1][tid] = 0; }

    const unsigned short* xgp = XG + (size_t)b * S_LEN * NGATE + j;
    float* ob = out + (size_t)b * S_LEN * HDIM + j;

    // interleaved write slot for this thread's h value (halves index)
    int wslot = ((j & 127) >> 3) * 16 + (j >> 7) * 8 + (j & 7);

    // prefetch t=0 gate inputs (lane pairs load same address - HW merges)
    unsigned short pz = xgp[0], pr = xgp[256], ph = xgp[512];
    float hm = 0.0f;  // fp32 master h (identical in both pair lanes)
    __syncthreads();

    for (int t = 0; t < S_LEN; ++t) {
        int cur = t & 1;
        float xz = h2f(pz), xr = h2f(pr), xh = h2f(ph);
        const unsigned short* nx = xgp + (size_t)((t + 1 < S_LEN) ? t + 1 : t) * NGATE;
        pz = nx[0]; pr = nx[256]; ph = nx[512];

        float az0 = 0.f, az1 = 0.f, ar0 = 0.f, ar1 = 0.f, ah0 = 0.f, ah1 = 0.f;
        const uint4* hrow = (const uint4*)hb[cur];  // 32 uint4 = 16 chunks x 2
#pragma unroll
        for (int c = 0; c < 16; c++) {
            uint4 hv = hrow[c * 2 + s];   // lane pair: A and A+16 (diff banks)
            int k = c * 4;
            az0 = dot2(hv.x, uz[k + 0], az0); az1 = dot2(hv.y, uz[k + 1], az1);
            ar0 = dot2(hv.x, ur[k + 0], ar0); ar1 = dot2(hv.y, ur[k + 1], ar1);
            ah0 = dot2(hv.x, uh[k + 0], ah0); ah1 = dot2(hv.y, uh[k + 1], ah1);
            az0 = dot2(hv.z, uz[k + 2], az0); az1 = dot2(hv.w, uz[k + 3], az1);
            ar0 = dot2(hv.z, ur[k + 2], ar0); ar1 = dot2(hv.w, ur[k + 3], ar1);
            ah0 = dot2(hv.z, uh[k + 2], ah0); ah1 = dot2(hv.w, uh[k + 3], ah1);
        }
        // combine K-halves across the adjacent-lane pair (DPP swap)
        float sz = az0 + az1, sr = ar0 + ar1, sh = ah0 + ah1;
        sz += __shfl_xor(sz, 1, 64);
        sr += __shfl_xor(sr, 1, 64);
        sh += __shfl_xor(sh, 1, 64);

        float z = sigmoid_fast(xz + sz);
        float r = sigmoid_fast(xr + sr);
        float cand = tanh_fast(xh + r * (sh + buh_j));
        hm = (1.0f - z) * hm + z * cand;

        if (s == 0) {
            ob[(size_t)t * HDIM] = hm;
            hb[cur ^ 1][wslot] = f2h(hm);
        }
        __syncthreads();
    }
}

// ---------------- launch ----------------

extern "C" void kernel_launch(void* const* d_in, const int* in_sizes, int n_in,
                              void* d_out, int out_size, void* d_ws, size_t ws_size,
                              hipStream_t stream) {
    const float* x   = (const float*)d_in[0];
    const float* Wz  = (const float*)d_in[1];
    const float* bz  = (const float*)d_in[2];
    const float* Wr  = (const float*)d_in[3];
    const float* br  = (const float*)d_in[4];
    const float* Wh  = (const float*)d_in[5];
    const float* bh  = (const float*)d_in[6];
    const float* Uz  = (const float*)d_in[7];
    const float* buz = (const float*)d_in[8];
    const float* Ur  = (const float*)d_in[9];
    const float* bur = (const float*)d_in[10];
    const float* Uh  = (const float*)d_in[11];
    const float* buh = (const float*)d_in[12];

    char* ws = (char*)d_ws;
    // layout: Xh 64MiB | XG 192MiB | Wt 384KiB | Upk 384KiB | biascat 3KiB
    unsigned short* Xh = (unsigned short*)(ws);
    unsigned short* XG = (unsigned short*)(ws + 67108864);
    unsigned short* Wt = (unsigned short*)(ws + 268435456);
    unsigned*       Upk = (unsigned*)(ws + 268828672);
    float*          biascat = (float*)(ws + 269221888);

    k_cvt_x<<<32768, 256, 0, stream>>>((const float4*)x, (ushort4*)Xh);
    k_prep_w<<<768, 256, 0, stream>>>(Wz, Wr, Wh, bz, br, bh, buz, bur, Wt, biascat);
    k_prep_u<<<384, 256, 0, stream>>>(Uz, Ur, Uh, Upk);

    dim3 g1(M_TOTAL / 128, NGATE / 128);
    k_gemm_x<<<g1, 256, 0, stream>>>(Xh, Wt, biascat, XG);

    k_gru<<<BATCH, 512, 0, stream>>>(Upk, XG, buh, (float*)d_out);
}

// Round 7
// 2279.377 us; speedup vs baseline: 1.2323x; 1.0305x over previous
//
#include <hip/hip_runtime.h>
#include <hip/hip_bf16.h>
#include <hip/hip_fp16.h>

// GRU B=64 S=2048 I=256 H=256, fp32 in/out.
// Phase 1: XG[m][768] = x@[Wz|Wr|Wh] + bias  (fp16 MFMA, fp32 accum)
// Phase 2 (R7): recurrence on the MATRIX pipe. R4/R6 showed the VALU path
//   is stuck at ~2x its paper rate (AGPR-read tax / dot2 half-rate:
//   VALUBusy 75% of 2600cy vs 930cy hand count). Per step per batch row:
//   h@[Uz|Ur|Uh] = (1x256)x(256x768) done as M=16-padded MFMA
//   16x16x32_f16: 48 MFMA/step/WG, 6 per wave (2 N-tile "triples" z,r,h).
//   U lives as pre-swizzled B-fragments in 192 regs/thread (MFMA reads
//   them directly -- no per-use move). h_prev broadcast from 512B LDS;
//   MFMA rows are independent so pad rows read garbage harmlessly.
//   All lanes compute identical nonlinearity (D rows 4,8,12 = row 0);
//   lanes 0-15 store. 1 barrier/step. Layouts verified by phase-1 GEMM.

#define S_LEN 2048
#define BATCH 64
#define HDIM  256
#define NGATE 768
#define M_TOTAL (BATCH * S_LEN)  // 131072

typedef _Float16 h2_t __attribute__((ext_vector_type(2)));
typedef _Float16 h8_t __attribute__((ext_vector_type(8)));
typedef float    f32x4 __attribute__((ext_vector_type(4)));

static __device__ __forceinline__ float h2f(unsigned short s) {
    _Float16 h; __builtin_memcpy(&h, &s, 2); return (float)h;
}
static __device__ __forceinline__ unsigned short f2h(float f) {
    _Float16 h = (_Float16)f; unsigned short s; __builtin_memcpy(&s, &h, 2); return s;
}

static __device__ __forceinline__ float sigmoid_fast(float x) {
    float e = __builtin_amdgcn_exp2f(-1.44269504088896341f * x);
    return __builtin_amdgcn_rcpf(1.0f + e);
}
static __device__ __forceinline__ float tanh_fast(float x) {
    return 2.0f * sigmoid_fast(2.0f * x) - 1.0f;
}

// ---------------- prep kernels ----------------

__global__ void k_cvt_x(const float4* __restrict__ x4, ushort4* __restrict__ xh4) {
    int i = blockIdx.x * blockDim.x + threadIdx.x;
    float4 v = x4[i];
    ushort4 o;
    o.x = f2h(v.x); o.y = f2h(v.y); o.z = f2h(v.z); o.w = f2h(v.w);
    xh4[i] = o;
}

__global__ void k_prep_w(const float* __restrict__ Wz, const float* __restrict__ Wr,
                         const float* __restrict__ Wh,
                         const float* __restrict__ bz, const float* __restrict__ br,
                         const float* __restrict__ bh,
                         const float* __restrict__ buz, const float* __restrict__ bur,
                         unsigned short* __restrict__ Wt, float* __restrict__ biascat) {
    int n = blockIdx.x;       // 0..767
    int k = threadIdx.x;      // 0..255
    int g = n >> 8, h = n & 255;
    const float* W = (g == 0) ? Wz : (g == 1) ? Wr : Wh;
    Wt[n * 256 + k] = f2h(W[k * 256 + h]);
    if (k == 0) {
        float bias = (g == 0) ? (bz[h] + buz[h]) : (g == 1) ? (br[h] + bur[h]) : bh[h];
        biascat[n] = bias;
    }
}

// B-fragment layout for mfma_f32_16x16x32_f16 (same mapping the passing
// phase-1 GEMM uses): lane l supplies B[k][col] with col = nt*16 + (l&15),
// k = ks*32 + (l>>4)*8 + e (e=0..7).
// Ufrag[(((g*16+nt)*8+ks)*64 + l)*8 + e] = fp16(U_g[k][col])
__global__ void k_prep_ufrag(const float* __restrict__ Uz, const float* __restrict__ Ur,
                             const float* __restrict__ Uh,
                             unsigned short* __restrict__ Ufrag) {
    int idx = blockIdx.x * 256 + threadIdx.x;  // [0, 196608)
    int e  = idx & 7;
    int l  = (idx >> 3) & 63;
    int ks = (idx >> 9) & 7;
    int nt = (idx >> 12) & 15;
    int g  = idx >> 16;
    const float* U = (g == 0) ? Uz : (g == 1) ? Ur : Uh;
    int k   = ks * 32 + (l >> 4) * 8 + e;
    int col = nt * 16 + (l & 15);
    Ufrag[idx] = f2h(U[k * 256 + col]);
}

// ---------------- phase 1: input GEMM ----------------

#define LDT 264  // 256 + 8 halves per LDS row

__global__ __launch_bounds__(256) void k_gemm_x(const unsigned short* __restrict__ Xh,
                                                const unsigned short* __restrict__ Wt,
                                                const float* __restrict__ biascat,
                                                unsigned short* __restrict__ XG) {
    __shared__ unsigned short As[128 * LDT];
    __shared__ unsigned short Bs[128 * LDT];
    int tid = threadIdx.x;
    int m0 = blockIdx.x * 128;
    int n0 = blockIdx.y * 128;

    {
        const unsigned short* ga = Xh + (size_t)m0 * 256;
        const unsigned short* gb = Wt + (size_t)n0 * 256;
#pragma unroll
        for (int i = 0; i < 16; i++) {
            int chunk = tid + i * 256;
            int row = chunk >> 5;
            int c8  = (chunk & 31) * 8;
            uint4 va = *(const uint4*)(ga + row * 256 + c8);
            *(uint4*)(As + row * LDT + c8) = va;
            uint4 vb = *(const uint4*)(gb + row * 256 + c8);
            *(uint4*)(Bs + row * LDT + c8) = vb;
        }
    }
    __syncthreads();

    int lane = tid & 63, wv = tid >> 6;
    int mw = (wv & 1) * 64, nw = (wv >> 1) * 64;
    int lr = lane & 15, lg = lane >> 4;

    f32x4 acc[4][4] = {};
#pragma unroll
    for (int k = 0; k < 8; k++) {
        h8_t a[4], b[4];
#pragma unroll
        for (int i = 0; i < 4; i++)
            a[i] = *(const h8_t*)(As + (mw + i * 16 + lr) * LDT + k * 32 + lg * 8);
#pragma unroll
        for (int jj = 0; jj < 4; jj++)
            b[jj] = *(const h8_t*)(Bs + (nw + jj * 16 + lr) * LDT + k * 32 + lg * 8);
#pragma unroll
        for (int i = 0; i < 4; i++)
#pragma unroll
            for (int jj = 0; jj < 4; jj++)
                acc[i][jj] = __builtin_amdgcn_mfma_f32_16x16x32_f16(a[i], b[jj], acc[i][jj], 0, 0, 0);
    }

#pragma unroll
    for (int jj = 0; jj < 4; jj++) {
        int gcol = n0 + nw + jj * 16 + lr;
        float bias = biascat[gcol];
#pragma unroll
        for (int i = 0; i < 4; i++) {
            int grow = m0 + mw + i * 16 + lg * 4;
#pragma unroll
            for (int r = 0; r < 4; r++) {
                XG[(size_t)(grow + r) * NGATE + gcol] = f2h(acc[i][jj][r] + bias);
            }
        }
    }
}

// ---------------- phase 2: recurrence (MFMA) ----------------
// 64 WGs (one per batch row) x 512 threads (8 waves, 2/SIMD).
// Wave w owns N-tiles nt0=2w, nt1=2w+1 (16 gate-columns each, all 3 gates).

__global__ __launch_bounds__(512) __attribute__((amdgpu_waves_per_eu(2, 2)))
void k_gru(const unsigned short* __restrict__ Ufrag,
           const unsigned short* __restrict__ XG,
           const float* __restrict__ buh,
           float* __restrict__ out) {
    __shared__ __align__(16) unsigned short hb[2][256];
    int tid = threadIdx.x;
    int lane = tid & 63, w = tid >> 6;
    int l4 = lane >> 4, lc = lane & 15;
    int b = blockIdx.x;
    int nt0 = 2 * w, nt1 = 2 * w + 1;

    // preamble: 48 B-fragments (192 VGPRs) = U[:, wave's 32 cols], 3 gates
    h8_t uf[3][2][8];
#pragma unroll
    for (int g = 0; g < 3; g++)
#pragma unroll
        for (int i = 0; i < 2; i++)
#pragma unroll
            for (int ks = 0; ks < 8; ks++)
                uf[g][i][ks] = *(const h8_t*)(Ufrag +
                    ((size_t)((g * 16 + (2 * w + i)) * 8 + ks) * 64 + lane) * 8);
    // pin: asm-touched values cannot be rematerialized into the loop
#pragma unroll
    for (int g = 0; g < 3; g++)
#pragma unroll
        for (int i = 0; i < 2; i++)
#pragma unroll
            for (int ks = 0; ks < 8; ks++)
                asm volatile("" : "+v"(uf[g][i][ks]));

    float buh0 = buh[nt0 * 16 + lc];
    float buh1 = buh[nt1 * 16 + lc];

    if (tid < 256) { hb[0][tid] = 0; hb[1][tid] = 0; }

    const unsigned short* xb = XG + (size_t)b * S_LEN * NGATE;
    float* ob = out + (size_t)b * S_LEN * HDIM;

    // t=0 gate-input prefetch (cols nt*16+lc; valid in every lane)
    unsigned short pz0 = xb[0 * 256 + nt0 * 16 + lc];
    unsigned short pr0 = xb[1 * 256 + nt0 * 16 + lc];
    unsigned short ph0 = xb[2 * 256 + nt0 * 16 + lc];
    unsigned short pz1 = xb[0 * 256 + nt1 * 16 + lc];
    unsigned short pr1 = xb[1 * 256 + nt1 * 16 + lc];
    unsigned short ph1 = xb[2 * 256 + nt1 * 16 + lc];
    float hm0 = 0.0f, hm1 = 0.0f;  // fp32 master h for the 2 owned cols
    __syncthreads();

    for (int t = 0; t < S_LEN; ++t) {
        int cur = t & 1;
        const unsigned short* hrow = hb[cur];

        f32x4 az = {}, ar = {}, ah = {};   // triple nt0
        f32x4 bz = {}, br = {}, bh = {};   // triple nt1
#pragma unroll
        for (int ks = 0; ks < 8; ks++) {
            // A-frag: h[k], k = ks*32 + l4*8 + e; same for all 16 lanes of a
            // group -> broadcast read, 4 distinct 16B addrs, conflict-free.
            // A rows 1..15 replicate row 0 -> D rows all equal (harmless).
            h8_t a = *(const h8_t*)(hrow + ks * 32 + l4 * 8);
            az = __builtin_amdgcn_mfma_f32_16x16x32_f16(a, uf[0][0][ks], az, 0, 0, 0);
            ar = __builtin_amdgcn_mfma_f32_16x16x32_f16(a, uf[1][0][ks], ar, 0, 0, 0);
            ah = __builtin_amdgcn_mfma_f32_16x16x32_f16(a, uf[2][0][ks], ah, 0, 0, 0);
            bz = __builtin_amdgcn_mfma_f32_16x16x32_f16(a, uf[0][1][ks], bz, 0, 0, 0);
            br = __builtin_amdgcn_mfma_f32_16x16x32_f16(a, uf[1][1][ks], br, 0, 0, 0);
            bh = __builtin_amdgcn_mfma_f32_16x16x32_f16(a, uf[2][1][ks], bh, 0, 0, 0);
        }

        // nonlinearity (identical in all lanes; D reg0 of every lane-group
        // holds the same h.U value for col lc of the tile)
        float z0 = sigmoid_fast(h2f(pz0) + az[0]);
        float r0 = sigmoid_fast(h2f(pr0) + ar[0]);
        float c0 = tanh_fast(h2f(ph0) + r0 * (ah[0] + buh0));
        hm0 = (1.0f - z0) * hm0 + z0 * c0;

        float z1 = sigmoid_fast(h2f(pz1) + bz[0]);
        float r1 = sigmoid_fast(h2f(pr1) + br[0]);
        float c1 = tanh_fast(h2f(ph1) + r1 * (bh[0] + buh1));
        hm1 = (1.0f - z1) * hm1 + z1 * c1;

        // prefetch next step's x
        const unsigned short* xn = xb + (size_t)((t + 1 < S_LEN) ? t + 1 : t) * NGATE;
        pz0 = xn[0 * 256 + nt0 * 16 + lc];
        pr0 = xn[1 * 256 + nt0 * 16 + lc];
        ph0 = xn[2 * 256 + nt0 * 16 + lc];
        pz1 = xn[0 * 256 + nt1 * 16 + lc];
        pr1 = xn[1 * 256 + nt1 * 16 + lc];
        ph1 = xn[2 * 256 + nt1 * 16 + lc];

        if (lane < 16) {
            ob[(size_t)t * HDIM + nt0 * 16 + lc] = hm0;
            ob[(size_t)t * HDIM + nt1 * 16 + lc] = hm1;
            hb[cur ^ 1][nt0 * 16 + lc] = f2h(hm0);
            hb[cur ^ 1][nt1 * 16 + lc] = f2h(hm1);
        }
        __syncthreads();
    }
}

// ---------------- launch ----------------

extern "C" void kernel_launch(void* const* d_in, const int* in_sizes, int n_in,
                              void* d_out, int out_size, void* d_ws, size_t ws_size,
                              hipStream_t stream) {
    const float* x   = (const float*)d_in[0];
    const float* Wz  = (const float*)d_in[1];
    const float* bz  = (const float*)d_in[2];
    const float* Wr  = (const float*)d_in[3];
    const float* br  = (const float*)d_in[4];
    const float* Wh  = (const float*)d_in[5];
    const float* bh  = (const float*)d_in[6];
    const float* Uz  = (const float*)d_in[7];
    const float* buz = (const float*)d_in[8];
    const float* Ur  = (const float*)d_in[9];
    const float* bur = (const float*)d_in[10];
    const float* Uh  = (const float*)d_in[11];
    const float* buh = (const float*)d_in[12];

    char* ws = (char*)d_ws;
    // layout: Xh 64MiB | XG 192MiB | Wt 384KiB | Ufrag 384KiB | biascat 3KiB
    unsigned short* Xh = (unsigned short*)(ws);
    unsigned short* XG = (unsigned short*)(ws + 67108864);
    unsigned short* Wt = (unsigned short*)(ws + 268435456);
    unsigned short* Ufrag = (unsigned short*)(ws + 268828672);
    float*          biascat = (float*)(ws + 269221888);

    k_cvt_x<<<32768, 256, 0, stream>>>((const float4*)x, (ushort4*)Xh);
    k_prep_w<<<768, 256, 0, stream>>>(Wz, Wr, Wh, bz, br, bh, buz, bur, Wt, biascat);
    k_prep_ufrag<<<768, 256, 0, stream>>>(Uz, Ur, Uh, Ufrag);

    dim3 g1(M_TOTAL / 128, NGATE / 128);
    k_gemm_x<<<g1, 256, 0, stream>>>(Xh, Wt, biascat, XG);

    k_gru<<<BATCH, 512, 0, stream>>>(Ufrag, XG, buh, (float*)d_out);
}

// Round 8
// 1550.881 us; speedup vs baseline: 1.8112x; 1.4697x over previous
//
#include <hip/hip_runtime.h>
#include <hip/hip_bf16.h>
#include <hip/hip_fp16.h>

// GRU B=64 S=2048 I=256 H=256, fp32 in/out.
// Phase 1: XG[m][768] = x@[Wz|Wr|Wh] + bias  (fp16 MFMA, fp32 accum)
// Phase 2 (R8): recurrence on matrix pipe with INT8 K=64 MFMA.
//   R7 (fp16 16x16x32, 2150us): per-SIMD pipe cost is 18.5cy/MFMA (NOT
//   4.85 -- that was per-CU). 96 MFMA/SIMD/step = 1776cy floor; observed
//   2520cy. Padding waste (M=1 of 16) is structural; only K-per-inst cuts
//   the count. mfma_i32_16x16x64_i8: 48/SIMD x 20.4cy = 979cy floor.
//   h bounded in (-1,1) -> h_q = rn(h*127); U per-column scales; i32
//   accum exact. Master h stays fp32 in regs; only the h->U GEMM is i8.
//   uf = 96 regs (fits VGPRs, no AGPR read tax).

#define S_LEN 2048
#define BATCH 64
#define HDIM  256
#define NGATE 768
#define M_TOTAL (BATCH * S_LEN)  // 131072

typedef _Float16 h8_t __attribute__((ext_vector_type(8)));
typedef float    f32x4 __attribute__((ext_vector_type(4)));
typedef int      i32x4 __attribute__((ext_vector_type(4)));

static __device__ __forceinline__ float h2f(unsigned short s) {
    _Float16 h; __builtin_memcpy(&h, &s, 2); return (float)h;
}
static __device__ __forceinline__ unsigned short f2h(float f) {
    _Float16 h = (_Float16)f; unsigned short s; __builtin_memcpy(&s, &h, 2); return s;
}

static __device__ __forceinline__ float sigmoid_fast(float x) {
    float e = __builtin_amdgcn_exp2f(-1.44269504088896341f * x);
    return __builtin_amdgcn_rcpf(1.0f + e);
}
static __device__ __forceinline__ float tanh_fast(float x) {
    return 2.0f * sigmoid_fast(2.0f * x) - 1.0f;
}

// ---------------- prep kernels ----------------

__global__ void k_cvt_x(const float4* __restrict__ x4, ushort4* __restrict__ xh4) {
    int i = blockIdx.x * blockDim.x + threadIdx.x;
    float4 v = x4[i];
    ushort4 o;
    o.x = f2h(v.x); o.y = f2h(v.y); o.z = f2h(v.z); o.w = f2h(v.w);
    xh4[i] = o;
}

__global__ void k_prep_w(const float* __restrict__ Wz, const float* __restrict__ Wr,
                         const float* __restrict__ Wh,
                         const float* __restrict__ bz, const float* __restrict__ br,
                         const float* __restrict__ bh,
                         const float* __restrict__ buz, const float* __restrict__ bur,
                         unsigned short* __restrict__ Wt, float* __restrict__ biascat) {
    int n = blockIdx.x;       // 0..767
    int k = threadIdx.x;      // 0..255
    int g = n >> 8, h = n & 255;
    const float* W = (g == 0) ? Wz : (g == 1) ? Wr : Wh;
    Wt[n * 256 + k] = f2h(W[k * 256 + h]);
    if (k == 0) {
        float bias = (g == 0) ? (bz[h] + buz[h]) : (g == 1) ? (br[h] + bur[h]) : bh[h];
        biascat[n] = bias;
    }
}

// int8 B-fragments for mfma_i32_16x16x64_i8 + per-column descale factors.
// Lane l supplies B[k][col]: col = nt*16 + (l&15), k = ks*64 + (l>>4)*16 + e,
// e = 0..15 (bytes k-ascending within the 16B lane fragment).
// Ufrag[(((g*16+nt)*4+ks)*64 + l)*16 + e] = round(U_g[k][col] * s_col)
// invU[g*256+col] = maxk|U| / (127*127)  (descale: preact = D * invU)
__global__ void k_prep_uq(const float* __restrict__ Uz, const float* __restrict__ Ur,
                          const float* __restrict__ Uh,
                          signed char* __restrict__ Ufrag, float* __restrict__ invU) {
    int blk = blockIdx.x;           // g*256 + col
    int g = blk >> 8, col = blk & 255;
    int k = threadIdx.x;            // 0..255
    const float* U = (g == 0) ? Uz : (g == 1) ? Ur : Uh;
    float v = U[k * 256 + col];
    __shared__ float red[256];
    red[k] = fabsf(v);
    __syncthreads();
    for (int off = 128; off > 0; off >>= 1) {
        if (k < off) red[k] = fmaxf(red[k], red[k + off]);
        __syncthreads();
    }
    float m = red[0];
    float s = (m > 0.0f) ? 127.0f / m : 0.0f;
    int q = __float2int_rn(v * s);
    q = max(-127, min(127, q));
    int ks = k >> 6, l4 = (k >> 4) & 3, e = k & 15;
    int l = l4 * 16 + (col & 15), nt = col >> 4;
    Ufrag[((size_t)(((g * 16 + nt) * 4 + ks) * 64 + l)) * 16 + e] = (signed char)q;
    if (k == 0) invU[g * 256 + col] = m * (1.0f / 16129.0f);
}

// ---------------- phase 1: input GEMM ----------------

#define LDT 264  // 256 + 8 halves per LDS row

__global__ __launch_bounds__(256) void k_gemm_x(const unsigned short* __restrict__ Xh,
                                                const unsigned short* __restrict__ Wt,
                                                const float* __restrict__ biascat,
                                                unsigned short* __restrict__ XG) {
    __shared__ unsigned short As[128 * LDT];
    __shared__ unsigned short Bs[128 * LDT];
    int tid = threadIdx.x;
    int m0 = blockIdx.x * 128;
    int n0 = blockIdx.y * 128;

    {
        const unsigned short* ga = Xh + (size_t)m0 * 256;
        const unsigned short* gb = Wt + (size_t)n0 * 256;
#pragma unroll
        for (int i = 0; i < 16; i++) {
            int chunk = tid + i * 256;
            int row = chunk >> 5;
            int c8  = (chunk & 31) * 8;
            uint4 va = *(const uint4*)(ga + row * 256 + c8);
            *(uint4*)(As + row * LDT + c8) = va;
            uint4 vb = *(const uint4*)(gb + row * 256 + c8);
            *(uint4*)(Bs + row * LDT + c8) = vb;
        }
    }
    __syncthreads();

    int lane = tid & 63, wv = tid >> 6;
    int mw = (wv & 1) * 64, nw = (wv >> 1) * 64;
    int lr = lane & 15, lg = lane >> 4;

    f32x4 acc[4][4] = {};
#pragma unroll
    for (int k = 0; k < 8; k++) {
        h8_t a[4], b[4];
#pragma unroll
        for (int i = 0; i < 4; i++)
            a[i] = *(const h8_t*)(As + (mw + i * 16 + lr) * LDT + k * 32 + lg * 8);
#pragma unroll
        for (int jj = 0; jj < 4; jj++)
            b[jj] = *(const h8_t*)(Bs + (nw + jj * 16 + lr) * LDT + k * 32 + lg * 8);
#pragma unroll
        for (int i = 0; i < 4; i++)
#pragma unroll
            for (int jj = 0; jj < 4; jj++)
                acc[i][jj] = __builtin_amdgcn_mfma_f32_16x16x32_f16(a[i], b[jj], acc[i][jj], 0, 0, 0);
    }

#pragma unroll
    for (int jj = 0; jj < 4; jj++) {
        int gcol = n0 + nw + jj * 16 + lr;
        float bias = biascat[gcol];
#pragma unroll
        for (int i = 0; i < 4; i++) {
            int grow = m0 + mw + i * 16 + lg * 4;
#pragma unroll
            for (int r = 0; r < 4; r++) {
                XG[(size_t)(grow + r) * NGATE + gcol] = f2h(acc[i][jj][r] + bias);
            }
        }
    }
}

// ---------------- phase 2: recurrence (i8 MFMA) ----------------
// 64 WGs (one per batch row) x 512 threads (8 waves, 2/SIMD).
// Wave w owns N-tiles nt0=2w, nt1=2w+1 (16 gate-columns each, all 3 gates).
// h_q (int8, 256B) double-buffered in LDS; A-frag = 16B broadcast read.

__global__ __launch_bounds__(512) __attribute__((amdgpu_waves_per_eu(2, 2)))
void k_gru(const i32x4* __restrict__ Ufrag,
           const float* __restrict__ invU,
           const unsigned short* __restrict__ XG,
           const float* __restrict__ buh,
           float* __restrict__ out) {
    __shared__ __align__(16) signed char hb[2][256];
    int tid = threadIdx.x;
    int lane = tid & 63, w = tid >> 6;
    int l4 = lane >> 4, lc = lane & 15;
    int b = blockIdx.x;
    int nt0 = 2 * w, nt1 = 2 * w + 1;
    int c0 = nt0 * 16 + lc, c1 = nt1 * 16 + lc;

    // preamble: 24 i8 B-fragments (96 VGPRs) = U[:, wave's 32 cols], 3 gates
    i32x4 uf[3][2][4];
#pragma unroll
    for (int g = 0; g < 3; g++)
#pragma unroll
        for (int i = 0; i < 2; i++)
#pragma unroll
            for (int ks = 0; ks < 4; ks++)
                uf[g][i][ks] = Ufrag[(size_t)((g * 16 + (2 * w + i)) * 4 + ks) * 64 + lane];
    // pin: asm-touched values cannot be rematerialized into the loop
#pragma unroll
    for (int g = 0; g < 3; g++)
#pragma unroll
        for (int i = 0; i < 2; i++)
#pragma unroll
            for (int ks = 0; ks < 4; ks++)
                asm volatile("" : "+v"(uf[g][i][ks]));

    float invz0 = invU[0 * 256 + c0], invr0 = invU[1 * 256 + c0], invh0 = invU[2 * 256 + c0];
    float invz1 = invU[0 * 256 + c1], invr1 = invU[1 * 256 + c1], invh1 = invU[2 * 256 + c1];
    float buh0 = buh[c0], buh1 = buh[c1];

    if (tid < 128) ((int*)hb)[tid] = 0;

    const unsigned short* xb = XG + (size_t)b * S_LEN * NGATE;
    float* ob = out + (size_t)b * S_LEN * HDIM;

    // t=0 gate-input prefetch (valid in every lane)
    unsigned short pz0 = xb[0 * 256 + c0], pr0 = xb[1 * 256 + c0], ph0 = xb[2 * 256 + c0];
    unsigned short pz1 = xb[0 * 256 + c1], pr1 = xb[1 * 256 + c1], ph1 = xb[2 * 256 + c1];
    float hm0 = 0.0f, hm1 = 0.0f;  // fp32 master h for the 2 owned cols
    __syncthreads();

    for (int t = 0; t < S_LEN; ++t) {
        int cur = t & 1;
        const signed char* hrow = hb[cur];

        i32x4 az = {}, ar = {}, ah = {};   // triple nt0
        i32x4 bz = {}, br = {}, bh = {};   // triple nt1
#pragma unroll
        for (int ks = 0; ks < 4; ks++) {
            // A-frag: h_q[k], k = ks*64 + l4*16 + e (16B broadcast per lane
            // group, 4 distinct addrs, conflict-free). Rows all identical.
            i32x4 a = *(const i32x4*)(hrow + ks * 64 + l4 * 16);
            az = __builtin_amdgcn_mfma_i32_16x16x64_i8(a, uf[0][0][ks], az, 0, 0, 0);
            ar = __builtin_amdgcn_mfma_i32_16x16x64_i8(a, uf[1][0][ks], ar, 0, 0, 0);
            ah = __builtin_amdgcn_mfma_i32_16x16x64_i8(a, uf[2][0][ks], ah, 0, 0, 0);
            bz = __builtin_amdgcn_mfma_i32_16x16x64_i8(a, uf[0][1][ks], bz, 0, 0, 0);
            br = __builtin_amdgcn_mfma_i32_16x16x64_i8(a, uf[1][1][ks], br, 0, 0, 0);
            bh = __builtin_amdgcn_mfma_i32_16x16x64_i8(a, uf[2][1][ks], bh, 0, 0, 0);
        }

        // nonlinearity (identical across lanes; D rows replicate row 0)
        float z0 = sigmoid_fast(h2f(pz0) + (float)az[0] * invz0);
        float r0 = sigmoid_fast(h2f(pr0) + (float)ar[0] * invr0);
        float cd0 = tanh_fast(h2f(ph0) + r0 * ((float)ah[0] * invh0 + buh0));
        hm0 = (1.0f - z0) * hm0 + z0 * cd0;

        float z1 = sigmoid_fast(h2f(pz1) + (float)bz[0] * invz1);
        float r1 = sigmoid_fast(h2f(pr1) + (float)br[0] * invr1);
        float cd1 = tanh_fast(h2f(ph1) + r1 * ((float)bh[0] * invh1 + buh1));
        hm1 = (1.0f - z1) * hm1 + z1 * cd1;

        // prefetch next step's x
        const unsigned short* xn = xb + (size_t)((t + 1 < S_LEN) ? t + 1 : t) * NGATE;
        pz0 = xn[0 * 256 + c0]; pr0 = xn[1 * 256 + c0]; ph0 = xn[2 * 256 + c0];
        pz1 = xn[0 * 256 + c1]; pr1 = xn[1 * 256 + c1]; ph1 = xn[2 * 256 + c1];

        if (lane < 16) {
            ob[(size_t)t * HDIM + c0] = hm0;
            ob[(size_t)t * HDIM + c1] = hm1;
            hb[cur ^ 1][c0] = (signed char)__float2int_rn(hm0 * 127.0f);
            hb[cur ^ 1][c1] = (signed char)__float2int_rn(hm1 * 127.0f);
        }
        __syncthreads();
    }
}

// ---------------- launch ----------------

extern "C" void kernel_launch(void* const* d_in, const int* in_sizes, int n_in,
                              void* d_out, int out_size, void* d_ws, size_t ws_size,
                              hipStream_t stream) {
    const float* x   = (const float*)d_in[0];
    const float* Wz  = (const float*)d_in[1];
    const float* bz  = (const float*)d_in[2];
    const float* Wr  = (const float*)d_in[3];
    const float* br  = (const float*)d_in[4];
    const float* Wh  = (const float*)d_in[5];
    const float* bh  = (const float*)d_in[6];
    const float* Uz  = (const float*)d_in[7];
    const float* buz = (const float*)d_in[8];
    const float* Ur  = (const float*)d_in[9];
    const float* bur = (const float*)d_in[10];
    const float* Uh  = (const float*)d_in[11];
    const float* buh = (const float*)d_in[12];

    char* ws = (char*)d_ws;
    // layout: Xh 64MiB | XG 192MiB | Wt 384KiB | Ufrag 192KiB | biascat 3KiB | invU 3KiB
    unsigned short* Xh = (unsigned short*)(ws);
    unsigned short* XG = (unsigned short*)(ws + 67108864);
    unsigned short* Wt = (unsigned short*)(ws + 268435456);
    signed char*    Ufrag = (signed char*)(ws + 268828672);
    float*          biascat = (float*)(ws + 269221888);
    float*          invU = (float*)(ws + 269225984);

    k_cvt_x<<<32768, 256, 0, stream>>>((const float4*)x, (ushort4*)Xh);
    k_prep_w<<<768, 256, 0, stream>>>(Wz, Wr, Wh, bz, br, bh, buz, bur, Wt, biascat);
    k_prep_uq<<<768, 256, 0, stream>>>(Uz, Ur, Uh, Ufrag, invU);

    dim3 g1(M_TOTAL / 128, NGATE / 128);
    k_gemm_x<<<g1, 256, 0, stream>>>(Xh, Wt, biascat, XG);

    k_gru<<<BATCH, 512, 0, stream>>>((const i32x4*)Ufrag, invU, XG, buh, (float*)d_out);
}

// Round 9
// 1381.818 us; speedup vs baseline: 2.0328x; 1.1223x over previous
//
#include <hip/hip_runtime.h>
#include <hip/hip_bf16.h>
#include <hip/hip_fp16.h>

// GRU B=64 S=2048 I=256 H=256, fp32 in/out.
// Phase 1: XG[m][768] = x@[Wz|Wr|Wh] + bias  (fp16 MFMA, fp32 accum)
// Phase 2 (R9): i8 K=64 MFMA recurrence, 16 waves x 1 N-tile-triple.
//   R8 analysis: MfmaUtil 47% active -> 773cy pipe busy = 16.1cy/MFMA
//   (i8 peak ~5PF = 2x bf16; the 3944-TOPS ubench was a floor). True pipe
//   floor 768cy/step; measured 1645 -> 53% overhead = exposed ds_read +
//   serial tail + barrier. Fix: 4 waves/SIMD (1024 thr) so sibling MFMA
//   issue covers ds_read/tail latency; setprio(1) around MFMA (T5 -- waves
//   now phase-diverse); per-wave tail halved (1 triple).
//   Per-CU pipe work invariant (192 MFMA/step / 4 SIMD) -- only K-per-inst
//   or overhead can move; fp8/fp4 fail the error budget (h quant).

#define S_LEN 2048
#define BATCH 64
#define HDIM  256
#define NGATE 768
#define M_TOTAL (BATCH * S_LEN)  // 131072

typedef _Float16 h8_t __attribute__((ext_vector_type(8)));
typedef float    f32x4 __attribute__((ext_vector_type(4)));
typedef int      i32x4 __attribute__((ext_vector_type(4)));

static __device__ __forceinline__ float h2f(unsigned short s) {
    _Float16 h; __builtin_memcpy(&h, &s, 2); return (float)h;
}
static __device__ __forceinline__ unsigned short f2h(float f) {
    _Float16 h = (_Float16)f; unsigned short s; __builtin_memcpy(&s, &h, 2); return s;
}

static __device__ __forceinline__ float sigmoid_fast(float x) {
    float e = __builtin_amdgcn_exp2f(-1.44269504088896341f * x);
    return __builtin_amdgcn_rcpf(1.0f + e);
}
static __device__ __forceinline__ float tanh_fast(float x) {
    return 2.0f * sigmoid_fast(2.0f * x) - 1.0f;
}

// ---------------- prep kernels ----------------

__global__ void k_cvt_x(const float4* __restrict__ x4, ushort4* __restrict__ xh4) {
    int i = blockIdx.x * blockDim.x + threadIdx.x;
    float4 v = x4[i];
    ushort4 o;
    o.x = f2h(v.x); o.y = f2h(v.y); o.z = f2h(v.z); o.w = f2h(v.w);
    xh4[i] = o;
}

__global__ void k_prep_w(const float* __restrict__ Wz, const float* __restrict__ Wr,
                         const float* __restrict__ Wh,
                         const float* __restrict__ bz, const float* __restrict__ br,
                         const float* __restrict__ bh,
                         const float* __restrict__ buz, const float* __restrict__ bur,
                         unsigned short* __restrict__ Wt, float* __restrict__ biascat) {
    int n = blockIdx.x;       // 0..767
    int k = threadIdx.x;      // 0..255
    int g = n >> 8, h = n & 255;
    const float* W = (g == 0) ? Wz : (g == 1) ? Wr : Wh;
    Wt[n * 256 + k] = f2h(W[k * 256 + h]);
    if (k == 0) {
        float bias = (g == 0) ? (bz[h] + buz[h]) : (g == 1) ? (br[h] + bur[h]) : bh[h];
        biascat[n] = bias;
    }
}

// int8 B-fragments for mfma_i32_16x16x64_i8 + per-column descale factors.
// Lane l supplies B[k][col]: col = nt*16 + (l&15), k = ks*64 + (l>>4)*16 + e,
// e = 0..15 (bytes k-ascending within the 16B lane fragment).
// Ufrag[(((g*16+nt)*4+ks)*64 + l)*16 + e] = round(U_g[k][col] * s_col)
// invU[g*256+col] = maxk|U| / (127*127)  (descale: preact = D * invU)
__global__ void k_prep_uq(const float* __restrict__ Uz, const float* __restrict__ Ur,
                          const float* __restrict__ Uh,
                          signed char* __restrict__ Ufrag, float* __restrict__ invU) {
    int blk = blockIdx.x;           // g*256 + col
    int g = blk >> 8, col = blk & 255;
    int k = threadIdx.x;            // 0..255
    const float* U = (g == 0) ? Uz : (g == 1) ? Ur : Uh;
    float v = U[k * 256 + col];
    __shared__ float red[256];
    red[k] = fabsf(v);
    __syncthreads();
    for (int off = 128; off > 0; off >>= 1) {
        if (k < off) red[k] = fmaxf(red[k], red[k + off]);
        __syncthreads();
    }
    float m = red[0];
    float s = (m > 0.0f) ? 127.0f / m : 0.0f;
    int q = __float2int_rn(v * s);
    q = max(-127, min(127, q));
    int ks = k >> 6, l4 = (k >> 4) & 3, e = k & 15;
    int l = l4 * 16 + (col & 15), nt = col >> 4;
    Ufrag[((size_t)(((g * 16 + nt) * 4 + ks) * 64 + l)) * 16 + e] = (signed char)q;
    if (k == 0) invU[g * 256 + col] = m * (1.0f / 16129.0f);
}

// ---------------- phase 1: input GEMM ----------------

#define LDT 264  // 256 + 8 halves per LDS row

__global__ __launch_bounds__(256) void k_gemm_x(const unsigned short* __restrict__ Xh,
                                                const unsigned short* __restrict__ Wt,
                                                const float* __restrict__ biascat,
                                                unsigned short* __restrict__ XG) {
    __shared__ unsigned short As[128 * LDT];
    __shared__ unsigned short Bs[128 * LDT];
    int tid = threadIdx.x;
    int m0 = blockIdx.x * 128;
    int n0 = blockIdx.y * 128;

    {
        const unsigned short* ga = Xh + (size_t)m0 * 256;
        const unsigned short* gb = Wt + (size_t)n0 * 256;
#pragma unroll
        for (int i = 0; i < 16; i++) {
            int chunk = tid + i * 256;
            int row = chunk >> 5;
            int c8  = (chunk & 31) * 8;
            uint4 va = *(const uint4*)(ga + row * 256 + c8);
            *(uint4*)(As + row * LDT + c8) = va;
            uint4 vb = *(const uint4*)(gb + row * 256 + c8);
            *(uint4*)(Bs + row * LDT + c8) = vb;
        }
    }
    __syncthreads();

    int lane = tid & 63, wv = tid >> 6;
    int mw = (wv & 1) * 64, nw = (wv >> 1) * 64;
    int lr = lane & 15, lg = lane >> 4;

    f32x4 acc[4][4] = {};
#pragma unroll
    for (int k = 0; k < 8; k++) {
        h8_t a[4], b[4];
#pragma unroll
        for (int i = 0; i < 4; i++)
            a[i] = *(const h8_t*)(As + (mw + i * 16 + lr) * LDT + k * 32 + lg * 8);
#pragma unroll
        for (int jj = 0; jj < 4; jj++)
            b[jj] = *(const h8_t*)(Bs + (nw + jj * 16 + lr) * LDT + k * 32 + lg * 8);
#pragma unroll
        for (int i = 0; i < 4; i++)
#pragma unroll
            for (int jj = 0; jj < 4; jj++)
                acc[i][jj] = __builtin_amdgcn_mfma_f32_16x16x32_f16(a[i], b[jj], acc[i][jj], 0, 0, 0);
    }

#pragma unroll
    for (int jj = 0; jj < 4; jj++) {
        int gcol = n0 + nw + jj * 16 + lr;
        float bias = biascat[gcol];
#pragma unroll
        for (int i = 0; i < 4; i++) {
            int grow = m0 + mw + i * 16 + lg * 4;
#pragma unroll
            for (int r = 0; r < 4; r++) {
                XG[(size_t)(grow + r) * NGATE + gcol] = f2h(acc[i][jj][r] + bias);
            }
        }
    }
}

// ---------------- phase 2: recurrence (i8 MFMA, 16 waves) ----------------
// 64 WGs (one per batch row) x 1024 threads (16 waves, 4/SIMD).
// Wave w owns N-tile nt=w (16 gate-columns, all 3 gates): 12 MFMA/wave/step.

__global__ __launch_bounds__(1024) __attribute__((amdgpu_waves_per_eu(4, 4)))
void k_gru(const i32x4* __restrict__ Ufrag,
           const float* __restrict__ invU,
           const unsigned short* __restrict__ XG,
           const float* __restrict__ buh,
           float* __restrict__ out) {
    __shared__ __align__(16) signed char hb[2][256];
    int tid = threadIdx.x;
    int lane = tid & 63, w = tid >> 6;      // w = N-tile index, 0..15
    int l4 = lane >> 4, lc = lane & 15;
    int b = blockIdx.x;
    int c = w * 16 + lc;                     // owned gate-column (per gate)

    // preamble: 12 i8 B-fragments (48 VGPRs) = U[:, wave's 16 cols], 3 gates
    i32x4 uf[3][4];
#pragma unroll
    for (int g = 0; g < 3; g++)
#pragma unroll
        for (int ks = 0; ks < 4; ks++)
            uf[g][ks] = Ufrag[(size_t)((g * 16 + w) * 4 + ks) * 64 + lane];
    // pin: asm-touched values cannot be rematerialized into the loop
#pragma unroll
    for (int g = 0; g < 3; g++)
#pragma unroll
        for (int ks = 0; ks < 4; ks++)
            asm volatile("" : "+v"(uf[g][ks]));

    float invz = invU[0 * 256 + c], invr = invU[1 * 256 + c], invh = invU[2 * 256 + c];
    float buh_c = buh[c];

    if (tid < 128) ((int*)hb)[tid] = 0;

    const unsigned short* xb = XG + (size_t)b * S_LEN * NGATE;
    float* ob = out + (size_t)b * S_LEN * HDIM;

    // t=0 gate-input prefetch (valid in every lane)
    unsigned short pz = xb[0 * 256 + c], pr = xb[1 * 256 + c], ph = xb[2 * 256 + c];
    float hm = 0.0f;  // fp32 master h for the owned column
    __syncthreads();

    for (int t = 0; t < S_LEN; ++t) {
        int cur = t & 1;
        const signed char* hrow = hb[cur];

        i32x4 az = {}, ar = {}, ah = {};
        __builtin_amdgcn_s_setprio(1);
#pragma unroll
        for (int ks = 0; ks < 4; ks++) {
            // A-frag: h_q[k], k = ks*64 + l4*16 + e (16B broadcast per lane
            // group, 4 distinct addrs, conflict-free). Rows all identical.
            i32x4 a = *(const i32x4*)(hrow + ks * 64 + l4 * 16);
            az = __builtin_amdgcn_mfma_i32_16x16x64_i8(a, uf[0][ks], az, 0, 0, 0);
            ar = __builtin_amdgcn_mfma_i32_16x16x64_i8(a, uf[1][ks], ar, 0, 0, 0);
            ah = __builtin_amdgcn_mfma_i32_16x16x64_i8(a, uf[2][ks], ah, 0, 0, 0);
        }
        __builtin_amdgcn_s_setprio(0);

        // nonlinearity (identical across lanes; D rows replicate row 0)
        float z = sigmoid_fast(h2f(pz) + (float)az[0] * invz);
        float r = sigmoid_fast(h2f(pr) + (float)ar[0] * invr);
        float cd = tanh_fast(h2f(ph) + r * ((float)ah[0] * invh + buh_c));
        hm = (1.0f - z) * hm + z * cd;

        // prefetch next step's x
        const unsigned short* xn = xb + (size_t)((t + 1 < S_LEN) ? t + 1 : t) * NGATE;
        pz = xn[0 * 256 + c]; pr = xn[1 * 256 + c]; ph = xn[2 * 256 + c];

        if (lane < 16) {
            ob[(size_t)t * HDIM + c] = hm;
            hb[cur ^ 1][c] = (signed char)__float2int_rn(hm * 127.0f);
        }
        __syncthreads();
    }
}

// ---------------- launch ----------------

extern "C" void kernel_launch(void* const* d_in, const int* in_sizes, int n_in,
                              void* d_out, int out_size, void* d_ws, size_t ws_size,
                              hipStream_t stream) {
    const float* x   = (const float*)d_in[0];
    const float* Wz  = (const float*)d_in[1];
    const float* bz  = (const float*)d_in[2];
    const float* Wr  = (const float*)d_in[3];
    const float* br  = (const float*)d_in[4];
    const float* Wh  = (const float*)d_in[5];
    const float* bh  = (const float*)d_in[6];
    const float* Uz  = (const float*)d_in[7];
    const float* buz = (const float*)d_in[8];
    const float* Ur  = (const float*)d_in[9];
    const float* bur = (const float*)d_in[10];
    const float* Uh  = (const float*)d_in[11];
    const float* buh = (const float*)d_in[12];

    char* ws = (char*)d_ws;
    // layout: Xh 64MiB | XG 192MiB | Wt 384KiB | Ufrag 192KiB | biascat 3KiB | invU 3KiB
    unsigned short* Xh = (unsigned short*)(ws);
    unsigned short* XG = (unsigned short*)(ws + 67108864);
    unsigned short* Wt = (unsigned short*)(ws + 268435456);
    signed char*    Ufrag = (signed char*)(ws + 268828672);
    float*          biascat = (float*)(ws + 269221888);
    float*          invU = (float*)(ws + 269225984);

    k_cvt_x<<<32768, 256, 0, stream>>>((const float4*)x, (ushort4*)Xh);
    k_prep_w<<<768, 256, 0, stream>>>(Wz, Wr, Wh, bz, br, bh, buz, bur, Wt, biascat);
    k_prep_uq<<<768, 256, 0, stream>>>(Uz, Ur, Uh, Ufrag, invU);

    dim3 g1(M_TOTAL / 128, NGATE / 128);
    k_gemm_x<<<g1, 256, 0, stream>>>(Xh, Wt, biascat, XG);

    k_gru<<<BATCH, 1024, 0, stream>>>((const i32x4*)Ufrag, invU, XG, buh, (float*)d_out);
}